// Round 8
// baseline (152.112 us; speedup 1.0000x reference)
//
#include <hip/hip_runtime.h>
#include <hip/hip_bf16.h>

#define B_  8
#define S_  4096
#define DM  1024
#define DO  1024

typedef __attribute__((ext_vector_type(4))) float f32x4;
typedef __attribute__((ext_vector_type(8))) short bf16x8;

__device__ inline unsigned int pkbf(float a, float b) {
    __hip_bfloat162 h = __float22bfloat162_rn(float2{a, b});
    union { __hip_bfloat162 h2; unsigned int u; } cv;
    cv.h2 = h;
    return cv.u;
}

// ================= fast path: pre-tiled bf16 operands, BK=32 =================
// Tile format (16 KB): [row:256][64 B], 16-byte k-group g (g=0..3) of row r at
// byte r*64 + ((g ^ ((r>>1)&3))<<4). Conflict-free for b128 frag reads
// (lanes 0-7 = rows r..r+7 hit 8 distinct 16B slots). This IS the LDS image.

__global__ __launch_bounds__(256) void prep_xpack(
    const float* __restrict__ X, unsigned short* __restrict__ xpack)
{
    const int kt = blockIdx.x, bm = blockIdx.y, b = blockIdx.z;   // kt:32, bm:16, b:8
    const int r = threadIdx.x;                                     // 0..255
    const float* src = X + ((size_t)(b * S_ + bm * 256 + r)) * DM + kt * 32;
    char* dst = (char*)xpack + ((size_t)((b * 16 + bm) * 32 + kt)) * 16384 + r * 64;
    const int q = (r >> 1) & 3;
    #pragma unroll
    for (int g = 0; g < 4; ++g) {
        float4 a = *reinterpret_cast<const float4*>(src + g * 8);
        float4 c = *reinterpret_cast<const float4*>(src + g * 8 + 4);
        uint4 u;
        u.x = pkbf(a.x, a.y); u.y = pkbf(a.z, a.w);
        u.z = pkbf(c.x, c.y); u.w = pkbf(c.z, c.w);
        *reinterpret_cast<uint4*>(dst + ((g ^ q) << 4)) = u;
    }
}

__global__ __launch_bounds__(256) void prep_wpack32(
    const float* __restrict__ W, const int* __restrict__ sel_idx,
    const float* __restrict__ sel_probs, unsigned short* __restrict__ wpack)
{
    const int kt = blockIdx.x, nb = blockIdx.y, b = blockIdx.z;   // kt:32, nb:4, b:8
    const int i0 = sel_idx[b*2+0], i1 = sel_idx[b*2+1];
    const float p0 = sel_probs[b*2+0], p1 = sel_probs[b*2+1];
    const int c = threadIdx.x;                                     // col 0..255
    const int o = nb * 256 + c;
    const float* w0 = W + (size_t)i0 * DM * DO + (size_t)(kt * 32) * DO + o;
    const float* w1 = W + (size_t)i1 * DM * DO + (size_t)(kt * 32) * DO + o;
    char* dst = (char*)wpack + ((size_t)((b * 4 + nb) * 32 + kt)) * 16384 + c * 64;
    const int q = (c >> 1) & 3;
    #pragma unroll
    for (int g = 0; g < 4; ++g) {
        float v[8];
        #pragma unroll
        for (int j = 0; j < 8; ++j)
            v[j] = p0 * w0[(size_t)(g * 8 + j) * DO] + p1 * w1[(size_t)(g * 8 + j) * DO];
        uint4 u;
        u.x = pkbf(v[0], v[1]); u.y = pkbf(v[2], v[3]);
        u.z = pkbf(v[4], v[5]); u.w = pkbf(v[6], v[7]);
        *reinterpret_cast<uint4*>(dst + ((g ^ q) << 4)) = u;
    }
}

__global__ __launch_bounds__(256) void prep_beff(
    const float* __restrict__ bias, const int* __restrict__ sel_idx,
    const float* __restrict__ sel_probs, float* __restrict__ beff)
{
    const int b = blockIdx.x;
    const int i0 = sel_idx[b*2+0], i1 = sel_idx[b*2+1];
    const float p0 = sel_probs[b*2+0], p1 = sel_probs[b*2+1];
    for (int o = threadIdx.x; o < DO; o += blockDim.x)
        beff[(size_t)b * DO + o] = p0 * bias[(size_t)i0 * DO + o]
                                 + p1 * bias[(size_t)i1 * DO + o];
}

// ---- GEMM: 256x256, BK=32, 8 waves (2Mx4N). Ring-of-4 per operand (128 KB),
// prefetch depth 3, counted vmcnt(8) per tile (loads stay in flight across
// barriers). Reads split around MFMA clusters. Zero VALU in loop. ----
__global__ __launch_bounds__(512, 2) void gemmr(
    const unsigned short* __restrict__ xpack, const unsigned short* __restrict__ wpack,
    const float* __restrict__ beff, float* __restrict__ out)
{
    extern __shared__ char lds[];   // ringA: s*16384 (s=0..3); ringB: 65536 + s*16384

    const int id = blockIdx.x;
    const int swz = (id & 7) * 64 + (id >> 3);  // XCD-chunked, bijective (512=8*64)
    const int b  = swz >> 6;
    const int bm = (swz >> 2) & 15;
    const int nb = swz & 3;

    const int t = threadIdx.x;
    const int wave = t >> 6, lane = t & 63;
    const int wm = wave >> 2, wnw = wave & 3;   // 2x4 grid, 128x64 out per wave
    const int fr = lane & 15, fq = lane >> 4;

    const char* xt = (const char*)xpack + ((size_t)((b * 16 + bm) * 32)) * 16384;
    const char* wt = (const char*)wpack + ((size_t)((b * 4 + nb) * 32)) * 16384;

    const int q   = (fr >> 1) & 3;
    const int rdA = (wm * 128 + fr) * 64 + ((fq ^ q) << 4);   // + slot + mf*1024
    const int rdB = (wnw * 64 + fr) * 64 + ((fq ^ q) << 4);   // + 65536 + slot + nf*1024

    f32x4 acc[8][4] = {};
    bf16x8 afLo[4], afHi[4], bkA[4], bkB[4];

#define GLOAD(SRC, DST)                                                        \
    __builtin_amdgcn_global_load_lds(                                          \
        (const __attribute__((address_space(1))) void*)(SRC),                  \
        (__attribute__((address_space(3))) void*)(DST), 16, 0, 0)

#define STAGE(KT, SLOT)                                                        \
    {   const char* ga = xt + (size_t)(KT) * 16384 + wave * 2048 + lane * 16;  \
        const char* gb = wt + (size_t)(KT) * 16384 + wave * 2048 + lane * 16;  \
        char* la = lds + (SLOT) + wave * 2048;                                 \
        char* lb = lds + 65536 + (SLOT) + wave * 2048;                         \
        GLOAD(ga, la); GLOAD(ga + 1024, la + 1024);                            \
        GLOAD(gb, lb); GLOAD(gb + 1024, lb + 1024); }

#define READ_BK(DST, SLOT)                                                     \
    _Pragma("unroll")                                                          \
    for (int nf = 0; nf < 4; ++nf)                                             \
        DST[nf] = *reinterpret_cast<const bf16x8*>(lds + 65536 + (SLOT) + rdB + nf * 1024);

#define READ_ALO(SLOT)                                                         \
    _Pragma("unroll")                                                          \
    for (int m = 0; m < 4; ++m)                                                \
        afLo[m] = *reinterpret_cast<const bf16x8*>(lds + (SLOT) + rdA + m * 1024);

#define READ_AHI(SLOT)                                                         \
    _Pragma("unroll")                                                          \
    for (int m = 0; m < 4; ++m)                                                \
        afHi[m] = *reinterpret_cast<const bf16x8*>(lds + (SLOT) + rdA + (4 + m) * 1024);

#define MFMA16(MB, AF, BK)                                                     \
    __builtin_amdgcn_s_setprio(1);                                             \
    _Pragma("unroll")                                                          \
    for (int m = 0; m < 4; ++m) {                                              \
        _Pragma("unroll")                                                      \
        for (int nf = 0; nf < 4; ++nf)                                         \
            acc[(MB)+m][nf] = __builtin_amdgcn_mfma_f32_16x16x32_bf16(         \
                AF[m], BK[nf], acc[(MB)+m][nf], 0, 0, 0);                      \
    }                                                                          \
    __builtin_amdgcn_s_setprio(0);

#define SB0 __builtin_amdgcn_sched_barrier(0)

// One K-tile body. WAITN: outstanding gloads allowed to remain in flight.
// lgkmcnt(0) before the barrier guarantees every read of a ring slot is
// complete one barrier before that slot's overwriting gloads can land.
#define BODY(KT, BKC, BKN, WAITN, DO_STAGE)                                    \
    {   if (DO_STAGE) { STAGE((KT) + 3, (((KT) + 3) & 3) * 16384); }           \
        SB0;                                                                   \
        MFMA16(0, afLo, BKC)                                                   \
        SB0;                                                                   \
        asm volatile("s_waitcnt vmcnt(" #WAITN ") lgkmcnt(0)" ::: "memory");   \
        __builtin_amdgcn_s_barrier();                                          \
        {   const int sN = (((KT) + 1) & 3) * 16384;                           \
            READ_BK(BKN, sN);                                                  \
            READ_ALO(sN);                                                      \
            SB0;                                                               \
            MFMA16(4, afHi, BKC)                                               \
            READ_AHI(sN); } }

    // ---------- prologue: stage tiles 0,1,2; read tile-0 fragments ----------
    STAGE(0, 0); STAGE(1, 16384); STAGE(2, 32768);
    asm volatile("s_waitcnt vmcnt(8)" ::: "memory");   // tile 0 landed
    __builtin_amdgcn_s_barrier();
    READ_BK(bkA, 0);
    READ_ALO(0);
    READ_AHI(0);

    // ---------- main loop: tiles 0..27 (double body, static parity) ----------
    #pragma unroll 1
    for (int kt = 0; kt < 28; kt += 2) {
        BODY(kt,     bkA, bkB, 8, true)
        BODY(kt + 1, bkB, bkA, 8, true)
    }
    // ---------- tail ----------
    BODY(28, bkA, bkB, 8, true)    // stages tile 31
    BODY(29, bkB, bkA, 4, false)
    BODY(30, bkA, bkB, 0, false)
    MFMA16(0, afLo, bkB)
    MFMA16(4, afHi, bkB)

    // ---------- epilogue: bias + sigmoid, fp32 store ----------
    const float* be = beff + (size_t)b * DO + nb * 256 + wnw * 64;
    float bv[4];
    #pragma unroll
    for (int nf = 0; nf < 4; ++nf) bv[nf] = be[nf * 16 + fr];

    float* ob = out + ((size_t)(b * S_ + bm * 256 + wm * 128)) * DO + nb * 256 + wnw * 64;
    #pragma unroll
    for (int mf = 0; mf < 8; ++mf) {
        #pragma unroll
        for (int nf = 0; nf < 4; ++nf) {
            const int col = nf * 16 + fr;
            #pragma unroll
            for (int r = 0; r < 4; ++r) {
                const int row = mf * 16 + fq * 4 + r;
                const float xv = acc[mf][nf][r] + bv[nf];
                ob[(size_t)row * DO + col] = 1.0f / (1.0f + __expf(-xv));
            }
        }
    }
#undef GLOAD
#undef STAGE
#undef READ_BK
#undef READ_ALO
#undef READ_AHI
#undef MFMA16
#undef SB0
#undef BODY
}

// ================= fallback path (round-5, known-pass) =================
__global__ __launch_bounds__(256) void prep_wpack_f(
    const float* __restrict__ W, const int* __restrict__ sel_idx,
    const float* __restrict__ sel_probs, unsigned short* __restrict__ wpack)
{
    const int kt = blockIdx.x, nb = blockIdx.y, b = blockIdx.z;
    const int i0 = sel_idx[b*2+0], i1 = sel_idx[b*2+1];
    const float p0 = sel_probs[b*2+0], p1 = sel_probs[b*2+1];
    const int t = threadIdx.x;
    const int col = t & 127;
    const int gh  = t >> 7;
    const int o = nb * 128 + col;
    const float* w0 = W + (size_t)i0 * DM * DO + (size_t)(kt * 32) * DO + o;
    const float* w1 = W + (size_t)i1 * DM * DO + (size_t)(kt * 32) * DO + o;
    char* tile = (char*)wpack + ((size_t)((b * 8 + nb) * 32 + kt)) * 8192;
    const int q = (col >> 1) & 3;
    #pragma unroll
    for (int gg = 0; gg < 2; ++gg) {
        const int g = gh * 2 + gg;
        float v[8];
        #pragma unroll
        for (int j = 0; j < 8; ++j)
            v[j] = p0 * w0[(size_t)(g * 8 + j) * DO] + p1 * w1[(size_t)(g * 8 + j) * DO];
        uint4 u;
        u.x = pkbf(v[0], v[1]); u.y = pkbf(v[2], v[3]);
        u.z = pkbf(v[4], v[5]); u.w = pkbf(v[6], v[7]);
        *reinterpret_cast<uint4*>(tile + col * 64 + ((g ^ q) << 4)) = u;
    }
}

__global__ __launch_bounds__(256, 4) void gemm4(
    const float* __restrict__ X, const unsigned short* __restrict__ wpack,
    const float* __restrict__ beff, float* __restrict__ out)
{
    __shared__ char lds[32768];
    const int id = blockIdx.x;
    const int swz = (id & 7) * 256 + (id >> 3);
    const int b  = swz >> 8;
    const int bm = (swz >> 3) & 31;
    const int nb = swz & 7;
    const int t = threadIdx.x;
    const int wave = t >> 6, lane = t & 63;
    const int wm = wave >> 1, wn = wave & 1;
    const int fr = lane & 15, fq = lane >> 4;
    const int s_row = t >> 1;
    const int s_h   = t & 1;
    const float* xrow = X + ((size_t)(b * S_ + bm * 128 + s_row)) * DM + s_h * 16;
    const int sq = (s_row >> 1) & 3;
    const int wrA0 = s_row * 64 + (((s_h * 2 + 0) ^ sq) << 4);
    const int wrA1 = s_row * 64 + (((s_h * 2 + 1) ^ sq) << 4);
    const char* wtile = (const char*)wpack + ((size_t)((b * 8 + nb) * 32)) * 8192;
    const int axor = (fr >> 1) & 3;
    const int rdA = (wm * 64 + fr) * 64 + ((fq ^ axor) << 4);
    const int rdB = (wn * 64 + fr) * 64 + ((fq ^ axor) << 4);
    f32x4 acc[4][4] = {};
    float4 ax0, ax1, ax2, ax3;
#define LOAD_X(KT)                                                            \
    {   const float* s = xrow + (KT) * 32;                                    \
        ax0 = *reinterpret_cast<const float4*>(s);                            \
        ax1 = *reinterpret_cast<const float4*>(s + 4);                        \
        ax2 = *reinterpret_cast<const float4*>(s + 8);                        \
        ax3 = *reinterpret_cast<const float4*>(s + 12); }
#define STAGE_B(KT, BOFF)                                                     \
    {   const char* gB = wtile + (size_t)(KT) * 8192;                         \
        _Pragma("unroll")                                                     \
        for (int r = 0; r < 2; ++r)                                           \
            __builtin_amdgcn_global_load_lds(                                 \
                (const __attribute__((address_space(1))) void*)(gB + (wave*2+r)*1024 + lane*16), \
                (__attribute__((address_space(3))) void*)(lds + (BOFF) + (wave*2+r)*1024),       \
                16, 0, 0); }
#define WRITE_A(AOFF)                                                         \
    {   uint4 u0, u1;                                                         \
        u0.x = pkbf(ax0.x, ax0.y); u0.y = pkbf(ax0.z, ax0.w);                 \
        u0.z = pkbf(ax1.x, ax1.y); u0.w = pkbf(ax1.z, ax1.w);                 \
        u1.x = pkbf(ax2.x, ax2.y); u1.y = pkbf(ax2.z, ax2.w);                 \
        u1.z = pkbf(ax3.x, ax3.y); u1.w = pkbf(ax3.z, ax3.w);                 \
        *reinterpret_cast<uint4*>(lds + (AOFF) + wrA0) = u0;                  \
        *reinterpret_cast<uint4*>(lds + (AOFF) + wrA1) = u1; }
    LOAD_X(0);
    __builtin_amdgcn_sched_barrier(0);
    STAGE_B(0, 16384);
    __builtin_amdgcn_sched_barrier(0);
    WRITE_A(0);
    __syncthreads();
    for (int kt = 0; kt < 32; ++kt) {
        const int cur = (kt & 1) * 8192;
        const int nxt = 8192 - cur;
        if (kt < 31) {
            LOAD_X(kt + 1);
            __builtin_amdgcn_sched_barrier(0);
            STAGE_B(kt + 1, 16384 + nxt);
            __builtin_amdgcn_sched_barrier(0);
        }
        bf16x8 bf[4];
        #pragma unroll
        for (int nf = 0; nf < 4; ++nf)
            bf[nf] = *reinterpret_cast<const bf16x8*>(lds + 16384 + cur + rdB + nf * 1024);
        #pragma unroll
        for (int m = 0; m < 4; ++m) {
            bf16x8 af = *reinterpret_cast<const bf16x8*>(lds + cur + rdA + m * 1024);
            #pragma unroll
            for (int nf = 0; nf < 4; ++nf)
                acc[m][nf] = __builtin_amdgcn_mfma_f32_16x16x32_bf16(af, bf[nf], acc[m][nf], 0, 0, 0);
        }
        if (kt < 31) { WRITE_A(nxt); }
        __syncthreads();
    }
    const float* be = beff + (size_t)b * DO + nb * 128 + wn * 64;
    float bv[4];
    #pragma unroll
    for (int nf = 0; nf < 4; ++nf) bv[nf] = be[nf * 16 + fr];
    float* ob = out + ((size_t)(b * S_ + bm * 128 + wm * 64)) * DO + nb * 128 + wn * 64;
    #pragma unroll
    for (int m = 0; m < 4; ++m) {
        #pragma unroll
        for (int nf = 0; nf < 4; ++nf) {
            const int col = nf * 16 + fr;
            #pragma unroll
            for (int r = 0; r < 4; ++r) {
                const int row = m * 16 + fq * 4 + r;
                const float xv = acc[m][nf][r] + bv[nf];
                ob[(size_t)row * DO + col] = 1.0f / (1.0f + __expf(-xv));
            }
        }
    }
#undef LOAD_X
#undef STAGE_B
#undef WRITE_A
}

extern "C" void kernel_launch(void* const* d_in, const int* in_sizes, int n_in,
                              void* d_out, int out_size, void* d_ws, size_t ws_size,
                              hipStream_t stream) {
    const float* tensor    = (const float*)d_in[0];
    const int*   sel_idx   = (const int*)d_in[1];
    const float* sel_probs = (const float*)d_in[2];
    const float* W         = (const float*)d_in[3];
    const float* bias      = (const float*)d_in[4];
    float* out = (float*)d_out;

    const size_t XP = (size_t)4096 * 16384;          // 64 MiB xpack (8 b x 16 bm x 32 kt)
    const size_t WP = (size_t)1024 * 16384;          // 16 MiB wpack (8 b x 4 nb x 32 kt)
    const size_t NEED = XP + WP + (size_t)B_ * DO * 4;

    if (ws_size >= NEED) {
        unsigned short* xpack = (unsigned short*)d_ws;
        unsigned short* wpack = (unsigned short*)((char*)d_ws + XP);
        float* beff = (float*)((char*)d_ws + XP + WP);

        hipFuncSetAttribute((const void*)gemmr,
                            hipFuncAttributeMaxDynamicSharedMemorySize, 131072);

        hipLaunchKernelGGL(prep_xpack, dim3(32, 16, 8), dim3(256), 0, stream,
                           tensor, xpack);
        hipLaunchKernelGGL(prep_wpack32, dim3(32, 4, 8), dim3(256), 0, stream,
                           W, sel_idx, sel_probs, wpack);
        hipLaunchKernelGGL(prep_beff, dim3(8), dim3(256), 0, stream,
                           bias, sel_idx, sel_probs, beff);
        hipLaunchKernelGGL(gemmr, dim3(512), dim3(512), 131072, stream,
                           xpack, wpack, beff, out);
    } else {
        unsigned short* wpack = (unsigned short*)d_ws;                   // 16 MiB
        float* beff = (float*)((char*)d_ws + (size_t)8 * 8 * 32 * 8192);
        hipLaunchKernelGGL(prep_wpack_f, dim3(32, 8, 8), dim3(256), 0, stream,
                           W, sel_idx, sel_probs, wpack);
        hipLaunchKernelGGL(prep_beff, dim3(8), dim3(256), 0, stream,
                           bias, sel_idx, sel_probs, beff);
        hipLaunchKernelGGL(gemm4, dim3(2048), dim3(256), 0, stream,
                           tensor, wpack, beff, out);
    }
}

// Round 9
// 146.672 us; speedup vs baseline: 1.0371x; 1.0371x over previous
//
#include <hip/hip_runtime.h>
#include <hip/hip_bf16.h>

#define B_  8
#define S_  4096
#define DM  1024
#define DO  1024

typedef __attribute__((ext_vector_type(4))) float f32x4;
typedef __attribute__((ext_vector_type(8))) short bf16x8;

__device__ inline unsigned int pkbf(float a, float b) {
    __hip_bfloat162 h = __float22bfloat162_rn(float2{a, b});
    union { __hip_bfloat162 h2; unsigned int u; } cv;
    cv.h2 = h;
    return cv.u;
}

// ================= fast path: pre-tiled bf16 operands, BK=32 =================
// Tile (8 KB): [row:128][64 B], 16-byte k-group g (0..3) of row r stored at
// byte r*64 + ((g ^ ((r>>1)&3))<<4). Conflict-free for b128 frag reads;
// linear global_load_lds image (rule 21). Measured 0 conflicts (r5/r8).

// xpack tile(b, bm:32, kt:32) at ((b*32+bm)*32+kt)*8192
__global__ __launch_bounds__(256) void prep_xpack(
    const float* __restrict__ X, unsigned short* __restrict__ xpack)
{
    const int bm = blockIdx.y, b = blockIdx.z;
    const int t = threadIdx.x;
    const int r  = t & 127;
    const int kt = blockIdx.x * 2 + (t >> 7);
    const float* src = X + ((size_t)(b * S_ + bm * 128 + r)) * DM + kt * 32;
    char* dst = (char*)xpack + ((size_t)((b * 32 + bm) * 32 + kt)) * 8192 + r * 64;
    const int q = (r >> 1) & 3;
    #pragma unroll
    for (int g = 0; g < 4; ++g) {
        float4 a = *reinterpret_cast<const float4*>(src + g * 8);
        float4 c = *reinterpret_cast<const float4*>(src + g * 8 + 4);
        uint4 u;
        u.x = pkbf(a.x, a.y); u.y = pkbf(a.z, a.w);
        u.z = pkbf(c.x, c.y); u.w = pkbf(c.z, c.w);
        *reinterpret_cast<uint4*>(dst + ((g ^ q) << 4)) = u;
    }
}

// wpack tile(b, nb:8, kt:32) at ((b*8+nb)*32+kt)*8192, inner [col:128][64B]
__global__ __launch_bounds__(256) void prep_wpack(
    const float* __restrict__ W, const int* __restrict__ sel_idx,
    const float* __restrict__ sel_probs, unsigned short* __restrict__ wpack)
{
    const int nb = blockIdx.y, b = blockIdx.z;
    const int i0 = sel_idx[b*2+0], i1 = sel_idx[b*2+1];
    const float p0 = sel_probs[b*2+0], p1 = sel_probs[b*2+1];
    const int t = threadIdx.x;
    const int c  = t & 127;
    const int kt = blockIdx.x * 2 + (t >> 7);
    const int o = nb * 128 + c;
    const float* w0 = W + (size_t)i0 * DM * DO + (size_t)(kt * 32) * DO + o;
    const float* w1 = W + (size_t)i1 * DM * DO + (size_t)(kt * 32) * DO + o;
    char* dst = (char*)wpack + ((size_t)((b * 8 + nb) * 32 + kt)) * 8192 + c * 64;
    const int q = (c >> 1) & 3;
    #pragma unroll
    for (int g = 0; g < 4; ++g) {
        float v[8];
        #pragma unroll
        for (int j = 0; j < 8; ++j)
            v[j] = p0 * w0[(size_t)(g * 8 + j) * DO] + p1 * w1[(size_t)(g * 8 + j) * DO];
        uint4 u;
        u.x = pkbf(v[0], v[1]); u.y = pkbf(v[2], v[3]);
        u.z = pkbf(v[4], v[5]); u.w = pkbf(v[6], v[7]);
        *reinterpret_cast<uint4*>(dst + ((g ^ q) << 4)) = u;
    }
}

__global__ __launch_bounds__(256) void prep_beff(
    const float* __restrict__ bias, const int* __restrict__ sel_idx,
    const float* __restrict__ sel_probs, float* __restrict__ beff)
{
    const int b = blockIdx.x;
    const int i0 = sel_idx[b*2+0], i1 = sel_idx[b*2+1];
    const float p0 = sel_probs[b*2+0], p1 = sel_probs[b*2+1];
    for (int o = threadIdx.x; o < DO; o += blockDim.x)
        beff[(size_t)b * DO + o] = p0 * bias[(size_t)i0 * DO + o]
                                 + p1 * bias[(size_t)i1 * DO + o];
}

// ---- GEMM: 128x128 tile, BK=32, 4 waves (2x2 of 64x64), dbuf 32KB static LDS.
// Zero VALU in loop; ~164 total regs -> 3-4 blocks/CU: sibling blocks hide
// each other's epilogue writes and barrier drains (m97/m114 regime). ----
__global__ __launch_bounds__(256, 4) void gemm128(
    const unsigned short* __restrict__ xpack, const unsigned short* __restrict__ wpack,
    const float* __restrict__ beff, float* __restrict__ out)
{
    __shared__ char lds[32768];   // A: 0/8192 ; B: 16384/24576

    const int id = blockIdx.x;
    const int swz = (id & 7) * 256 + (id >> 3);  // XCD-chunked, bijective (2048=8*256)
    const int b  = swz >> 8;
    const int bm = (swz >> 3) & 31;
    const int nb = swz & 7;   // nb fastest within an XCD: X-stripe + W-tile L2 reuse

    const int t = threadIdx.x;
    const int wave = t >> 6, lane = t & 63;
    const int wm = wave >> 1, wn = wave & 1;     // 2x2 grid, 64x64 out per wave
    const int fr = lane & 15, fq = lane >> 4;

    const char* xt = (const char*)xpack + ((size_t)((b * 32 + bm) * 32)) * 8192;
    const char* wt = (const char*)wpack + ((size_t)((b * 8 + nb) * 32)) * 8192;

    const int q   = (fr >> 1) & 3;
    const int rdA = (wm * 64 + fr) * 64 + ((fq ^ q) << 4);   // + cur + m*1024
    const int rdB = (wn * 64 + fr) * 64 + ((fq ^ q) << 4);   // + 16384 + cur + nf*1024

    f32x4 acc[4][4] = {};

#define GLOAD(SRC, DST)                                                        \
    __builtin_amdgcn_global_load_lds(                                          \
        (const __attribute__((address_space(1))) void*)(SRC),                  \
        (__attribute__((address_space(3))) void*)(DST), 16, 0, 0)

#define STAGE(KT, OFF)                                                         \
    {   const char* ga = xt + (size_t)(KT) * 8192 + wave * 2048 + lane * 16;   \
        const char* gb = wt + (size_t)(KT) * 8192 + wave * 2048 + lane * 16;   \
        char* la = lds + (OFF) + wave * 2048;                                  \
        char* lb = lds + 16384 + (OFF) + wave * 2048;                          \
        GLOAD(ga, la); GLOAD(ga + 1024, la + 1024);                            \
        GLOAD(gb, lb); GLOAD(gb + 1024, lb + 1024); }

    // ---------- prologue ----------
    STAGE(0, 0);
    __syncthreads();

    // ---------- main loop: m97-simple, cross-block TLP hides the drain ----------
    for (int kt = 0; kt < 32; ++kt) {
        const int cur = (kt & 1) * 8192;
        const int nxt = 8192 - cur;

        if (kt < 31) { STAGE(kt + 1, nxt); }

        bf16x8 bk[4];
        #pragma unroll
        for (int nf = 0; nf < 4; ++nf)
            bk[nf] = *reinterpret_cast<const bf16x8*>(lds + 16384 + cur + rdB + nf * 1024);
        #pragma unroll
        for (int m = 0; m < 4; ++m) {
            bf16x8 af = *reinterpret_cast<const bf16x8*>(lds + cur + rdA + m * 1024);
            #pragma unroll
            for (int nf = 0; nf < 4; ++nf)
                acc[m][nf] = __builtin_amdgcn_mfma_f32_16x16x32_bf16(af, bk[nf], acc[m][nf], 0, 0, 0);
        }

        __syncthreads();   // drains lgkm (frag reads) + vmcnt (staging)
    }

    // ---------- epilogue: bias + sigmoid, fp32 store ----------
    const float* be = beff + (size_t)b * DO + nb * 128 + wn * 64;
    float bv[4];
    #pragma unroll
    for (int nf = 0; nf < 4; ++nf) bv[nf] = be[nf * 16 + fr];

    float* ob = out + ((size_t)(b * S_ + bm * 128 + wm * 64)) * DO + nb * 128 + wn * 64;
    #pragma unroll
    for (int m = 0; m < 4; ++m) {
        #pragma unroll
        for (int nf = 0; nf < 4; ++nf) {
            const int col = nf * 16 + fr;
            #pragma unroll
            for (int r = 0; r < 4; ++r) {
                const int row = m * 16 + fq * 4 + r;
                const float xv = acc[m][nf][r] + bv[nf];
                ob[(size_t)row * DO + col] = 1.0f / (1.0f + __expf(-xv));
            }
        }
    }
#undef GLOAD
#undef STAGE
}

// ================= fallback path (known-pass, raw inputs) =================
__global__ __launch_bounds__(256) void prep_wpack_f(
    const float* __restrict__ W, const int* __restrict__ sel_idx,
    const float* __restrict__ sel_probs, unsigned short* __restrict__ wpack)
{
    const int kt = blockIdx.x, nb = blockIdx.y, b = blockIdx.z;
    const int i0 = sel_idx[b*2+0], i1 = sel_idx[b*2+1];
    const float p0 = sel_probs[b*2+0], p1 = sel_probs[b*2+1];
    const int t = threadIdx.x;
    const int col = t & 127;
    const int gh  = t >> 7;
    const int o = nb * 128 + col;
    const float* w0 = W + (size_t)i0 * DM * DO + (size_t)(kt * 32) * DO + o;
    const float* w1 = W + (size_t)i1 * DM * DO + (size_t)(kt * 32) * DO + o;
    char* tile = (char*)wpack + ((size_t)((b * 8 + nb) * 32 + kt)) * 8192;
    const int q = (col >> 1) & 3;
    #pragma unroll
    for (int gg = 0; gg < 2; ++gg) {
        const int g = gh * 2 + gg;
        float v[8];
        #pragma unroll
        for (int j = 0; j < 8; ++j)
            v[j] = p0 * w0[(size_t)(g * 8 + j) * DO] + p1 * w1[(size_t)(g * 8 + j) * DO];
        uint4 u;
        u.x = pkbf(v[0], v[1]); u.y = pkbf(v[2], v[3]);
        u.z = pkbf(v[4], v[5]); u.w = pkbf(v[6], v[7]);
        *reinterpret_cast<uint4*>(tile + col * 64 + ((g ^ q) << 4)) = u;
    }
}

__global__ __launch_bounds__(256, 4) void gemm4(
    const float* __restrict__ X, const unsigned short* __restrict__ wpack,
    const float* __restrict__ beff, float* __restrict__ out)
{
    __shared__ char lds[32768];
    const int id = blockIdx.x;
    const int swz = (id & 7) * 256 + (id >> 3);
    const int b  = swz >> 8;
    const int bm = (swz >> 3) & 31;
    const int nb = swz & 7;
    const int t = threadIdx.x;
    const int wave = t >> 6, lane = t & 63;
    const int wm = wave >> 1, wn = wave & 1;
    const int fr = lane & 15, fq = lane >> 4;
    const int s_row = t >> 1;
    const int s_h   = t & 1;
    const float* xrow = X + ((size_t)(b * S_ + bm * 128 + s_row)) * DM + s_h * 16;
    const int sq = (s_row >> 1) & 3;
    const int wrA0 = s_row * 64 + (((s_h * 2 + 0) ^ sq) << 4);
    const int wrA1 = s_row * 64 + (((s_h * 2 + 1) ^ sq) << 4);
    const char* wtile = (const char*)wpack + ((size_t)((b * 8 + nb) * 32)) * 8192;
    const int axor = (fr >> 1) & 3;
    const int rdA = (wm * 64 + fr) * 64 + ((fq ^ axor) << 4);
    const int rdB = (wn * 64 + fr) * 64 + ((fq ^ axor) << 4);
    f32x4 acc[4][4] = {};
    float4 ax0, ax1, ax2, ax3;
#define LOAD_X(KT)                                                            \
    {   const float* s = xrow + (KT) * 32;                                    \
        ax0 = *reinterpret_cast<const float4*>(s);                            \
        ax1 = *reinterpret_cast<const float4*>(s + 4);                        \
        ax2 = *reinterpret_cast<const float4*>(s + 8);                        \
        ax3 = *reinterpret_cast<const float4*>(s + 12); }
#define STAGE_B(KT, BOFF)                                                     \
    {   const char* gB = wtile + (size_t)(KT) * 8192;                         \
        _Pragma("unroll")                                                     \
        for (int r = 0; r < 2; ++r)                                           \
            __builtin_amdgcn_global_load_lds(                                 \
                (const __attribute__((address_space(1))) void*)(gB + (wave*2+r)*1024 + lane*16), \
                (__attribute__((address_space(3))) void*)(lds + (BOFF) + (wave*2+r)*1024),       \
                16, 0, 0); }
#define WRITE_A(AOFF)                                                         \
    {   uint4 u0, u1;                                                         \
        u0.x = pkbf(ax0.x, ax0.y); u0.y = pkbf(ax0.z, ax0.w);                 \
        u0.z = pkbf(ax1.x, ax1.y); u0.w = pkbf(ax1.z, ax1.w);                 \
        u1.x = pkbf(ax2.x, ax2.y); u1.y = pkbf(ax2.z, ax2.w);                 \
        u1.z = pkbf(ax3.x, ax3.y); u1.w = pkbf(ax3.z, ax3.w);                 \
        *reinterpret_cast<uint4*>(lds + (AOFF) + wrA0) = u0;                  \
        *reinterpret_cast<uint4*>(lds + (AOFF) + wrA1) = u1; }
    LOAD_X(0);
    __builtin_amdgcn_sched_barrier(0);
    STAGE_B(0, 16384);
    __builtin_amdgcn_sched_barrier(0);
    WRITE_A(0);
    __syncthreads();
    for (int kt = 0; kt < 32; ++kt) {
        const int cur = (kt & 1) * 8192;
        const int nxt = 8192 - cur;
        if (kt < 31) {
            LOAD_X(kt + 1);
            __builtin_amdgcn_sched_barrier(0);
            STAGE_B(kt + 1, 16384 + nxt);
            __builtin_amdgcn_sched_barrier(0);
        }
        bf16x8 bf[4];
        #pragma unroll
        for (int nf = 0; nf < 4; ++nf)
            bf[nf] = *reinterpret_cast<const bf16x8*>(lds + 16384 + cur + rdB + nf * 1024);
        #pragma unroll
        for (int m = 0; m < 4; ++m) {
            bf16x8 af = *reinterpret_cast<const bf16x8*>(lds + cur + rdA + m * 1024);
            #pragma unroll
            for (int nf = 0; nf < 4; ++nf)
                acc[m][nf] = __builtin_amdgcn_mfma_f32_16x16x32_bf16(af, bf[nf], acc[m][nf], 0, 0, 0);
        }
        if (kt < 31) { WRITE_A(nxt); }
        __syncthreads();
    }
    const float* be = beff + (size_t)b * DO + nb * 128 + wn * 64;
    float bv[4];
    #pragma unroll
    for (int nf = 0; nf < 4; ++nf) bv[nf] = be[nf * 16 + fr];
    float* ob = out + ((size_t)(b * S_ + bm * 128 + wm * 64)) * DO + nb * 128 + wn * 64;
    #pragma unroll
    for (int m = 0; m < 4; ++m) {
        #pragma unroll
        for (int nf = 0; nf < 4; ++nf) {
            const int col = nf * 16 + fr;
            #pragma unroll
            for (int r = 0; r < 4; ++r) {
                const int row = m * 16 + fq * 4 + r;
                const float xv = acc[m][nf][r] + bv[nf];
                ob[(size_t)row * DO + col] = 1.0f / (1.0f + __expf(-xv));
            }
        }
    }
#undef LOAD_X
#undef STAGE_B
#undef WRITE_A
}

extern "C" void kernel_launch(void* const* d_in, const int* in_sizes, int n_in,
                              void* d_out, int out_size, void* d_ws, size_t ws_size,
                              hipStream_t stream) {
    const float* tensor    = (const float*)d_in[0];
    const int*   sel_idx   = (const int*)d_in[1];
    const float* sel_probs = (const float*)d_in[2];
    const float* W         = (const float*)d_in[3];
    const float* bias      = (const float*)d_in[4];
    float* out = (float*)d_out;

    const size_t XP = (size_t)8192 * 8192;           // 64 MiB xpack (8 b x 32 bm x 32 kt)
    const size_t WP = (size_t)2048 * 8192;           // 16 MiB wpack (8 b x 8 nb x 32 kt)
    const size_t NEED = XP + WP + (size_t)B_ * DO * 4;

    if (ws_size >= NEED) {
        unsigned short* xpack = (unsigned short*)d_ws;
        unsigned short* wpack = (unsigned short*)((char*)d_ws + XP);
        float* beff = (float*)((char*)d_ws + XP + WP);

        hipLaunchKernelGGL(prep_xpack, dim3(16, 32, 8), dim3(256), 0, stream,
                           tensor, xpack);
        hipLaunchKernelGGL(prep_wpack, dim3(16, 8, 8), dim3(256), 0, stream,
                           W, sel_idx, sel_probs, wpack);
        hipLaunchKernelGGL(prep_beff, dim3(8), dim3(256), 0, stream,
                           bias, sel_idx, sel_probs, beff);
        hipLaunchKernelGGL(gemm128, dim3(2048), dim3(256), 0, stream,
                           xpack, wpack, beff, out);
    } else {
        unsigned short* wpack = (unsigned short*)d_ws;                   // 16 MiB
        float* beff = (float*)((char*)d_ws + (size_t)8 * 8 * 32 * 8192);
        hipLaunchKernelGGL(prep_wpack_f, dim3(32, 8, 8), dim3(256), 0, stream,
                           W, sel_idx, sel_probs, wpack);
        hipLaunchKernelGGL(prep_beff, dim3(8), dim3(256), 0, stream,
                           bias, sel_idx, sel_probs, beff);
        hipLaunchKernelGGL(gemm4, dim3(2048), dim3(256), 0, stream,
                           tensor, wpack, beff, out);
    }
}